// Round 2
// baseline (12982.675 us; speedup 1.0000x reference)
//
#include <hip/hip_runtime.h>
#include <math.h>

#define G_    1024
#define NPG   126
#define EPG   450
#define NN    (G_*NPG)      // 129024
#define EE    (G_*EPG)      // 460800
#define F_    126
#define EPSV  1e-5f
#define NCHUNK 8
#define CH    (NN/NCHUNK)   // 16128 nodes = 128 graphs per chunk

// ---------------- node embedding: h = x @ emb1_w + emb1_b ----------------
__global__ void k_embed(const float* __restrict__ x, const float* __restrict__ w,
                        const float* __restrict__ b, float* __restrict__ h) {
    int idx = blockIdx.x * blockDim.x + threadIdx.x;
    if (idx >= NN * F_) return;
    int n = idx / F_;
    int f = idx - n * F_;
    float v = b[f];
#pragma unroll
    for (int c = 0; c < 5; ++c) v += x[n * 5 + c] * w[c * F_ + f];
    h[idx] = v;
}

// ---------------- per-graph CSR build (one block per graph) ----------------
__global__ void k_build_csr(const int* __restrict__ src, const int* __restrict__ dst,
                            const int* __restrict__ attr,
                            int* __restrict__ deg, int* __restrict__ rstart,
                            int* __restrict__ epack) {
    int g = blockIdx.x;
    __shared__ int scnt[NPG];
    __shared__ int spos[NPG];
    int t = threadIdx.x;
    for (int j = t; j < NPG; j += blockDim.x) scnt[j] = 0;
    __syncthreads();
    int e0 = g * EPG;
    for (int i = t; i < EPG; i += blockDim.x) {
        int dl = dst[e0 + i] - g * NPG;
        atomicAdd(&scnt[dl], 1);
    }
    __syncthreads();
    if (t == 0) {
        int run = 0;
        for (int j = 0; j < NPG; ++j) { spos[j] = run; run += scnt[j]; }
    }
    __syncthreads();
    for (int j = t; j < NPG; j += blockDim.x) {
        deg[g * NPG + j]    = scnt[j];
        rstart[g * NPG + j] = e0 + spos[j];
    }
    __syncthreads();
    for (int j = t; j < NPG; j += blockDim.x) scnt[j] = 0;
    __syncthreads();
    for (int i = t; i < EPG; i += blockDim.x) {
        int e  = e0 + i;
        int dl = dst[e] - g * NPG;
        int p  = atomicAdd(&scnt[dl], 1);
        epack[e0 + spos[dl] + p] = src[e] | (attr[e] << 20);  // src < 2^17, attr < 10
    }
}

// ---------------- per-node degree scalers ----------------
__global__ void k_node_scalars(const int* __restrict__ deg, const int* __restrict__ deg_hist,
                               float* __restrict__ invc, float* __restrict__ ampv,
                               float* __restrict__ attv) {
    int n = blockIdx.x * blockDim.x + threadIdx.x;
    if (n >= NN) return;
    float sum = 0.f, sl = 0.f;
#pragma unroll
    for (int b = 0; b < 5; ++b) {
        float dh = (float)deg_hist[b];
        sum += dh;
        sl  += dh * logf((float)b + 1.f);
    }
    float avg_log = sl / sum;
    float c  = (float)deg[n];
    float cm = fmaxf(c, 1.f);
    invc[n] = 1.f / cm;
    float la = logf(cm + 1.f);
    ampv[n] = la / avg_log;
    attv[n] = avg_log / la;
}

// ---------------- edge-attr table: etab[l][a] = (edge_tab[a]@enc_w+enc_b)@We + pre_b ----------
__global__ void k_build_etab(const float* __restrict__ edge_tab, const float* __restrict__ enc_w,
                             const float* __restrict__ enc_b, const float* __restrict__ pre_w,
                             const float* __restrict__ pre_b, float* __restrict__ etab) {
    int l = blockIdx.x / 10, a = blockIdx.x % 10;
    __shared__ float tmp[F_];
    int t = threadIdx.x;
    if (t < F_) {
        float s = enc_b[l * F_ + t];
        for (int c = 0; c < 50; ++c) s += edge_tab[a * 50 + c] * enc_w[(l * 50 + c) * F_ + t];
        tmp[t] = s;
    }
    __syncthreads();
    if (t < F_) {
        float s = pre_b[l * F_ + t];
        for (int j = 0; j < F_; ++j) s += tmp[j] * pre_w[((size_t)l * 378 + 252 + j) * F_ + t];
        etab[(l * 10 + a) * F_ + t] = s;
    }
}

// ---------------- plain fp32 tiled GEMM: C[M,126] = A[M,K]@B[K,126] (+bias) ----------
__global__ __launch_bounds__(256) void k_gemm_plain(const float* __restrict__ A,
                                                    const float* __restrict__ B,
                                                    float* __restrict__ C, int M, int K,
                                                    const float* __restrict__ bias) {
    __shared__ float As[16][68];
    __shared__ float Bs[16][64];
    int tid = threadIdx.x;
    int m0 = blockIdx.y * 64;
    int n0 = blockIdx.x * 64;
    int tr = tid >> 4, tc = tid & 15;
    int ar = tid >> 4, ak = tid & 15;
    int br = tid >> 6, bn = tid & 63;
    float acc[4][4] = {};
    for (int k0 = 0; k0 < K; k0 += 16) {
#pragma unroll
        for (int i = 0; i < 4; ++i) {
            int row = m0 + ar + 16 * i;
            float v = 0.f;
            if (k0 + ak < K) v = A[(size_t)row * K + k0 + ak];
            As[ak][ar + 16 * i] = v;
        }
#pragma unroll
        for (int i = 0; i < 4; ++i) {
            int kk = k0 + br + 4 * i;
            float v = 0.f;
            if (kk < K && n0 + bn < F_) v = B[(size_t)kk * F_ + n0 + bn];
            Bs[br + 4 * i][bn] = v;
        }
        __syncthreads();
#pragma unroll
        for (int kk = 0; kk < 16; ++kk) {
            float a[4], b[4];
#pragma unroll
            for (int i = 0; i < 4; ++i) a[i] = As[kk][tr * 4 + i];
#pragma unroll
            for (int j = 0; j < 4; ++j) b[j] = Bs[kk][tc * 4 + j];
#pragma unroll
            for (int i = 0; i < 4; ++i)
#pragma unroll
                for (int j = 0; j < 4; ++j) acc[i][j] += a[i] * b[j];
        }
        __syncthreads();
    }
#pragma unroll
    for (int i = 0; i < 4; ++i) {
        int row = m0 + tr * 4 + i;
#pragma unroll
        for (int j = 0; j < 4; ++j) {
            int col = n0 + tc * 4 + j;
            if (col < F_) {
                float v = acc[i][j];
                if (bias) v += bias[col];
                C[(size_t)row * F_ + col] = v;
            }
        }
    }
}

// ------- fused post GEMM: C[CH,126] = [h | agg | agg*amp | agg*att] @ B[1638,126] + bias ------
__global__ __launch_bounds__(256) void k_gemm_post(const float* __restrict__ hc,
                                                   const float* __restrict__ aggb,
                                                   const float* __restrict__ ampc,
                                                   const float* __restrict__ attc,
                                                   const float* __restrict__ B,
                                                   const float* __restrict__ bias,
                                                   float* __restrict__ C) {
    __shared__ float As[16][68];
    __shared__ float Bs[16][64];
    int tid = threadIdx.x;
    int m0 = blockIdx.y * 64;
    int n0 = blockIdx.x * 64;
    int tr = tid >> 4, tc = tid & 15;
    int ar = tid >> 4, ak = tid & 15;
    int br = tid >> 6, bn = tid & 63;
    float acc[4][4] = {};
    for (int k0 = 0; k0 < 1638; k0 += 16) {
#pragma unroll
        for (int i = 0; i < 4; ++i) {
            int row = m0 + ar + 16 * i;
            int k = k0 + ak;
            float v = 0.f;
            if (k < 126) {
                v = hc[(size_t)row * F_ + k];
            } else if (k < 1638) {
                int kk = k - 126;
                int blk = kk / 504;          // 0: agg, 1: agg*amp, 2: agg*att
                int ka  = kk - blk * 504;
                v = aggb[(size_t)row * 504 + ka];
                if (blk == 1) v *= ampc[row];
                else if (blk == 2) v *= attc[row];
            }
            As[ak][ar + 16 * i] = v;
        }
#pragma unroll
        for (int i = 0; i < 4; ++i) {
            int kk = k0 + br + 4 * i;
            float v = 0.f;
            if (kk < 1638 && n0 + bn < F_) v = B[(size_t)kk * F_ + n0 + bn];
            Bs[br + 4 * i][bn] = v;
        }
        __syncthreads();
#pragma unroll
        for (int kk = 0; kk < 16; ++kk) {
            float a[4], b[4];
#pragma unroll
            for (int i = 0; i < 4; ++i) a[i] = As[kk][tr * 4 + i];
#pragma unroll
            for (int j = 0; j < 4; ++j) b[j] = Bs[kk][tc * 4 + j];
#pragma unroll
            for (int i = 0; i < 4; ++i)
#pragma unroll
                for (int j = 0; j < 4; ++j) acc[i][j] += a[i] * b[j];
        }
        __syncthreads();
    }
#pragma unroll
    for (int i = 0; i < 4; ++i) {
        int row = m0 + tr * 4 + i;
#pragma unroll
        for (int j = 0; j < 4; ++j) {
            int col = n0 + tc * 4 + j;
            if (col < F_) C[(size_t)row * F_ + col] = acc[i][j] + bias[col];
        }
    }
}

// ---------------- edge aggregation (one block per node; chunk-local) ----------------
// m_e = Pd[dst] + (Ps[src] + etab[attr]) = c + v ;  agg = [c+mean(v), c+min(v), c+max(v), std(v)]
__global__ void k_aggregate(const float* __restrict__ Pd, const float* __restrict__ Ps,
                            const float* __restrict__ etab_l,
                            const int* __restrict__ deg, const int* __restrict__ rstart,
                            const int* __restrict__ epack, const float* __restrict__ invc,
                            float* __restrict__ agg, int n_base) {
    int nl = blockIdx.x;          // chunk-local node
    int n  = n_base + nl;         // global node
    int f  = threadIdx.x;
    if (f >= F_) return;
    float* arow = agg + (size_t)nl * (4 * F_);
    int dg = deg[n];
    if (dg == 0) {
        arow[f] = 0.f; arow[F_ + f] = 0.f; arow[2 * F_ + f] = 0.f;
        arow[3 * F_ + f] = sqrtf(EPSV);
        return;
    }
    int rs = rstart[n];
    float c = Pd[(size_t)nl * F_ + f];
    float sum = 0.f, sumsq = 0.f, vmin = 3.4e38f, vmax = -3.4e38f;
    for (int e = 0; e < dg; ++e) {
        int pk = epack[rs + e];
        int s  = (pk & 0xFFFFF) - n_base;   // chunk-local src (same graph => same chunk)
        int a  = pk >> 20;
        float v = Ps[(size_t)s * F_ + f] + etab_l[a * F_ + f];
        sum += v; sumsq += v * v;
        vmin = fminf(vmin, v); vmax = fmaxf(vmax, v);
    }
    float ic  = invc[n];
    float mv  = sum * ic;
    float var = sumsq * ic - mv * mv;
    arow[f]          = c + mv;
    arow[F_ + f]     = c + vmin;
    arow[2 * F_ + f] = c + vmax;
    arow[3 * F_ + f] = sqrtf(fmaxf(var, 0.f) + EPSV);
}

// ---------------- BatchNorm stats / apply (in-place on h) ----------------
__global__ void k_bn_stats(const float* __restrict__ X, float* __restrict__ sums) {
    int f = threadIdx.x;
    if (f >= F_) return;
    int r0 = blockIdx.x * 64;
    float s = 0.f, s2 = 0.f;
    for (int r = 0; r < 64; ++r) {
        float v = X[(size_t)(r0 + r) * F_ + f];
        s += v; s2 += v * v;
    }
    atomicAdd(&sums[f], s);
    atomicAdd(&sums[F_ + f], s2);
}

__global__ void k_bn_apply(float* __restrict__ H, const float* __restrict__ sums,
                           const float* __restrict__ g, const float* __restrict__ b) {
    int idx = blockIdx.x * blockDim.x + threadIdx.x;
    if (idx >= NN * F_) return;
    int f = idx % F_;
    float mu  = sums[f] * (1.f / NN);
    float var = sums[F_ + f] * (1.f / NN) - mu * mu;
    float v = g[f] * (H[idx] - mu) * rsqrtf(var + EPSV) + b[f];
    H[idx] = fmaxf(v, 0.f);
}

// ---------------- pool (per-graph sum) + 4-layer MLP head ----------------
__global__ __launch_bounds__(128) void k_pool_mlp(const float* __restrict__ h,
        const float* __restrict__ w1, const float* __restrict__ b1,
        const float* __restrict__ w2, const float* __restrict__ b2,
        const float* __restrict__ w3, const float* __restrict__ b3,
        const float* __restrict__ w4, const float* __restrict__ b4,
        float* __restrict__ out) {
    int g = blockIdx.x;
    __shared__ float p[F_];
    __shared__ float z1[100];
    __shared__ float z2[50];
    __shared__ float z3[25];
    int t = threadIdx.x;
    if (t < F_) {
        float s = 0.f;
        const float* hb = h + (size_t)g * NPG * F_;
        for (int r = 0; r < NPG; ++r) s += hb[r * F_ + t];
        p[t] = s;
    }
    __syncthreads();
    if (t < 100) {
        float s = b1[t];
        for (int c = 0; c < F_; ++c) s += p[c] * w1[c * 100 + t];
        z1[t] = fmaxf(s, 0.f);
    }
    __syncthreads();
    if (t < 50) {
        float s = b2[t];
        for (int c = 0; c < 100; ++c) s += z1[c] * w2[c * 50 + t];
        z2[t] = fmaxf(s, 0.f);
    }
    __syncthreads();
    if (t < 25) {
        float s = b3[t];
        for (int c = 0; c < 50; ++c) s += z2[c] * w3[c * 25 + t];
        z3[t] = fmaxf(s, 0.f);
    }
    __syncthreads();
    if (t == 0) {
        float s = b4[0];
        for (int c = 0; c < 25; ++c) s += z3[c] * w4[c];
        out[g] = s;
    }
}

extern "C" void kernel_launch(void* const* d_in, const int* in_sizes, int n_in,
                              void* d_out, int out_size, void* d_ws, size_t ws_size,
                              hipStream_t stream) {
    const float* x        = (const float*)d_in[0];
    const int*   ei       = (const int*)d_in[1];
    const int*   src      = ei;
    const int*   dst      = ei + EE;
    const int*   eattr    = (const int*)d_in[2];
    const int*   deg_hist = (const int*)d_in[4];
    const float* emb1_w = (const float*)d_in[5];
    const float* emb1_b = (const float*)d_in[6];
    const float* edge_tab = (const float*)d_in[7];
    const float* enc_w  = (const float*)d_in[8];
    const float* enc_b  = (const float*)d_in[9];
    const float* pre_w  = (const float*)d_in[10];
    const float* pre_b  = (const float*)d_in[11];
    const float* post_w = (const float*)d_in[12];
    const float* post_b = (const float*)d_in[13];
    const float* lin_w  = (const float*)d_in[14];
    const float* lin_b  = (const float*)d_in[15];
    const float* bn_g   = (const float*)d_in[16];
    const float* bn_b   = (const float*)d_in[17];
    const float* w1 = (const float*)d_in[18];
    const float* b1 = (const float*)d_in[19];
    const float* w2 = (const float*)d_in[20];
    const float* b2 = (const float*)d_in[21];
    const float* w3 = (const float*)d_in[22];
    const float* b3 = (const float*)d_in[23];
    const float* w4 = (const float*)d_in[24];
    const float* b4 = (const float*)d_in[25];
    float* out = (float*)d_out;

    // workspace layout (~120.5 MiB total)
    float* ws   = (float*)d_ws;
    float* h    = ws;                        // NN*F          = 16,257,024
    float* Pd   = h    + (size_t)NN * F_;    // CH*F          =  2,032,128
    float* Ps   = Pd   + (size_t)CH * F_;    // CH*F          =  2,032,128
    float* aggb = Ps   + (size_t)CH * F_;    // CH*4F         =  8,128,512
    float* outA = aggb + (size_t)CH * 4 * F_;// CH*F          =  2,032,128
    float* etab = outA + (size_t)CH * F_;    // 4*10*F        =      5,040
    float* invc = etab + 4 * 10 * F_;        // NN
    float* ampv = invc + NN;                 // NN
    float* attv = ampv + NN;                 // NN
    float* bnsums = attv + NN;               // 256
    int*   deg    = (int*)(bnsums + 256);    // NN
    int*   rstart = deg + NN;                // NN
    int*   epack  = rstart + NN;             // EE

    k_embed<<<(NN * F_ + 255) / 256, 256, 0, stream>>>(x, emb1_w, emb1_b, h);
    k_build_csr<<<G_, 128, 0, stream>>>(src, dst, eattr, deg, rstart, epack);
    k_node_scalars<<<(NN + 255) / 256, 256, 0, stream>>>(deg, deg_hist, invc, ampv, attv);
    k_build_etab<<<40, 128, 0, stream>>>(edge_tab, enc_w, enc_b, pre_w, pre_b, etab);

    for (int l = 0; l < 4; ++l) {
        const float* Wi = pre_w + (size_t)l * 378 * F_;           // rows 0..125   (h[dst])
        const float* Wj = pre_w + ((size_t)l * 378 + 126) * F_;   // rows 126..251 (h[src])
        const float* Bp = post_w + (size_t)l * 1638 * F_;         // full post block

        for (int c = 0; c < NCHUNK; ++c) {
            float* hc = h + (size_t)c * CH * F_;
            int    nb = c * CH;
            k_gemm_plain<<<dim3(2, CH / 64), 256, 0, stream>>>(hc, Wi, Pd, CH, F_, nullptr);
            k_gemm_plain<<<dim3(2, CH / 64), 256, 0, stream>>>(hc, Wj, Ps, CH, F_, nullptr);
            k_aggregate<<<CH, 128, 0, stream>>>(Pd, Ps, etab + l * 10 * F_, deg, rstart,
                                                epack, invc, aggb, nb);
            k_gemm_post<<<dim3(2, CH / 64), 256, 0, stream>>>(hc, aggb, ampv + nb, attv + nb,
                                                              Bp, post_b + l * F_, outA);
            // lin; write back into h chunk (h rows of this chunk fully consumed above)
            k_gemm_plain<<<dim3(2, CH / 64), 256, 0, stream>>>(outA, lin_w + (size_t)l * F_ * F_,
                                                               hc, CH, F_, lin_b + l * F_);
        }
        // BatchNorm + ReLU in place on h
        hipMemsetAsync(bnsums, 0, 256 * sizeof(float), stream);
        k_bn_stats<<<NN / 64, 128, 0, stream>>>(h, bnsums);
        k_bn_apply<<<(NN * F_ + 255) / 256, 256, 0, stream>>>(h, bnsums,
                                                              bn_g + l * F_, bn_b + l * F_);
    }

    k_pool_mlp<<<G_, 128, 0, stream>>>(h, w1, b1, w2, b2, w3, b3, w4, b4, out);
}